// Round 14
// baseline (449.651 us; speedup 1.0000x reference)
//
#include <hip/hip_runtime.h>
#include <math.h>

// Problem constants
#define N_IMG 128
#define IC 8
#define IH 128
#define IW 128
#define OC 64
#define NG 16
#define PH 31
#define PW 31
#define GN_EPS 1e-5f
#define CSTR (IH * IW)      // channel stride in x
#define NBAND 4             // pool-row bands per image

typedef float f32x4 __attribute__((ext_vector_type(4)));
typedef short s16x8 __attribute__((ext_vector_type(8)));
typedef int   i32x4 __attribute__((ext_vector_type(4)));

// v_cvt_pk_bf16_f32: pack two f32 into one dword of 2 bf16 (RNE).
__device__ __forceinline__ unsigned cvt_pk_bf16(float a, float b) {
    unsigned r;
    asm("v_cvt_pk_bf16_f32 %0, %1, %2" : "=v"(r) : "v"(a), "v"(b));
    return r;
}
__device__ __forceinline__ float bf16lo_f(unsigned p) { return __uint_as_float(p << 16); }
__device__ __forceinline__ float bf16hi_f(unsigned p) { return __uint_as_float(p & 0xFFFF0000u); }

__device__ __forceinline__ s16x8 mk_frag(unsigned a, unsigned b, unsigned c, unsigned d) {
    union { i32x4 i; s16x8 s; } u;
    u.i = (i32x4){(int)a, (int)b, (int)c, (int)d};
    return u.s;
}

// split 8 f32 into hi/lo bf16 fragments: v ~= hi + lo to ~2^-17 rel.
__device__ __forceinline__ void split8(const float v[8], s16x8* hi, s16x8* lo) {
    unsigned h[4], l[4];
#pragma unroll
    for (int e = 0; e < 4; e++) {
        float a = v[2 * e], b = v[2 * e + 1];
        unsigned hp = cvt_pk_bf16(a, b);
        float ra = a - bf16lo_f(hp);
        float rb = b - bf16hi_f(hp);
        h[e] = hp;
        l[e] = cvt_pk_bf16(ra, rb);
    }
    *hi = mk_frag(h[0], h[1], h[2], h[3]);
    *lo = mk_frag(l[0], l[1], l[2], l[3]);
}

// PHASE 1 -- MFMA implicit-GEMM conv + pool-max + partial GN stats.
//
// ROUND-13 LESSON: per-cell cross-lane folds (96 shfl_xor per cell) were
// ~200 of 241us; MFMA itself only ~31us (MfmaUtil 13%). THIS VERSION
// TRANSPOSES THE TILE: B columns = 16 DIFFERENT pool cells (lane p15 =
// cell), the 16 window positions iterate in an outer loop. Consequences:
//  - pool max: same lane/reg = same (cell,channel) across positions ->
//    in-lane fmaxf, ZERO per-cell shuffles
//  - stats: per-lane accumulation, ONE butterfly per block
//  - B-gather: per pi, rows cached as aligned float4 pairs (coalesced);
//    pj window shift = free register renaming
//  - stores: lane = pw -> coalesced
// MFMA count / A-frags / split8 / per-output math IDENTICAL to R13
// (verified passing, absmax 0.00390625).
//
// Layout facts (HW-verified): A row / B col = lane&15; k-slot =
// 32*s + 16*h + (lane>>4)*4 + e (any bijective k-map valid when A,B agree);
// D: col = lane&15, row = (lane>>4)*4 + reg. K = ic*12 + kh*4 + kw
// (96 padded, kw=3 weight zero -> lane k-quad = 4 consecutive x cols).
// Split-bf16: D += Ah*Bh + Ah*Bl + Al*Bh.
__attribute__((amdgpu_waves_per_eu(2, 4)))
__launch_bounds__(256)
__global__ void conv_pool_mfma_phase1(const float* __restrict__ x,
                                      const float* __restrict__ conv_w,
                                      const float* __restrict__ conv_b,
                                      const float* __restrict__ gn_w,
                                      const float* __restrict__ gn_b,
                                      const float* __restrict__ scale,
                                      float* __restrict__ out,
                                      float* __restrict__ ws) {
    const int b = blockIdx.x;                  // 0..511
    const int wid = ((b & 7) << 6) | (b >> 3); // XCD swizzle (512 = 8x64)
    const int n = wid >> 2;
    const int band = wid & 3;
    const int tid = threadIdx.x;
    const int lane = tid & 63;
    const int wave = tid >> 6;
    const int p15 = lane & 15;                 // A-row / B-col / D-col index
    const int lg = lane >> 4;                  // k-quad selector / D row group

    __shared__ float gsum[4][NG][2];           // per-wave group partials

    const float* xn = x + (size_t)n * (IC * CSTR);

    // ---- per-lane k-quad decode: sh = s*2+half -> (ic, kh) ----
    int icA[6], khA[6], rowoffA[6];
#pragma unroll
    for (int sh = 0; sh < 6; sh++) {
        int s = sh >> 1, h = sh & 1;
        int k0 = 32 * s + 16 * h + 4 * lg;     // multiple of 4
        int ic = k0 / 12;
        int kk = k0 - 12 * ic;                 // 0,4,8
        int kh = kk >> 2;
        icA[sh] = ic; khA[sh] = kh;
        rowoffA[sh] = ic * CSTR + kh * IW;
    }

    // ---- A fragments: signed weights, hi/lo split, all 4 ch-sets ----
    s16x8 Ah[4][3], Al[4][3];
#pragma unroll
    for (int q = 0; q < 4; q++) {
        int c = q * 16 + p15;
        float sg = (gn_w[c] * scale[c] >= 0.f) ? 1.f : -1.f;
#pragma unroll
        for (int s = 0; s < 3; s++) {
            float wf[8];
#pragma unroll
            for (int h = 0; h < 2; h++) {
                int sh = s * 2 + h;
                int ic = icA[sh], kh = khA[sh];
#pragma unroll
                for (int kw = 0; kw < 4; kw++)
                    wf[h * 4 + kw] = (kw < 3)
                        ? conv_w[c * (IC * 9) + ic * 9 + kh * 3 + kw] * sg
                        : 0.f;
            }
            split8(wf, &Ah[q][s], &Al[q][s]);
        }
    }

    // ---- bias/sign for the ACC layout channels (q*16 + lg*4 + reg) ----
    float bias4[4][4], sgn4[4][4];
#pragma unroll
    for (int q = 0; q < 4; q++)
#pragma unroll
        for (int r = 0; r < 4; r++) {
            int c = q * 16 + 4 * lg + r;
            float sg = (gn_w[c] * scale[c] >= 0.f) ? 1.f : -1.f;
            sgn4[q][r] = sg;
            bias4[q][r] = conv_b[c] * sg;
        }

    float sA[4], ssA[4];
#pragma unroll
    for (int q = 0; q < 4; q++) { sA[q] = 0.f; ssA[q] = 0.f; }

    // ================= main tiles: 16 cells per tile, lane p15 = cell ====
    // Per image: 31 pool rows x 2 tiles (16 + 15 cells; last lane masked).
    // band<3: rows band*8..+7 (16 tiles); band 3: rows 24..30 (14 tiles).
    const int ntile = (band < 3) ? 16 : 14;
    const int phb = band * 8;

#pragma unroll 1
    for (int t = wave; t < ntile; t += 4) {
        const int ph = phb + (t >> 1);
        const int tb = (t & 1) * 16;
        const int pw = tb + p15;
        const int valid = (pw <= 30);
        const int pwc = valid ? pw : 30;       // clamp for safe loads
        const float msk = valid ? 1.f : 0.f;
        const float* xtile = xn + (4 * ph) * IW + 4 * pwc;

        f32x4 vmax[4];
#pragma unroll
        for (int q = 0; q < 4; q++)
            vmax[q] = (f32x4){-INFINITY, -INFINITY, -INFINITY, -INFINITY};

#pragma unroll
        for (int pi = 0; pi < 4; pi++) {
            // cache the 6 (s,h) x-rows: 8 aligned floats each (2x float4);
            // cols 4*pwc .. 4*pwc+7 (max col 127, in bounds)
            float row8[6][8];
#pragma unroll
            for (int sh = 0; sh < 6; sh++) {
                const float* p = xtile + rowoffA[sh] + pi * IW;
                float4 a = *(const float4*)p;
                float4 bq = *(const float4*)(p + 4);
                row8[sh][0] = a.x;  row8[sh][1] = a.y;
                row8[sh][2] = a.z;  row8[sh][3] = a.w;
                row8[sh][4] = bq.x; row8[sh][5] = bq.y;
                row8[sh][6] = bq.z; row8[sh][7] = bq.w;
            }
#pragma unroll
            for (int pj = 0; pj < 4; pj++) {
                f32x4 acc[4];
#pragma unroll
                for (int q = 0; q < 4; q++)
                    acc[q] = (f32x4){bias4[q][0], bias4[q][1],
                                     bias4[q][2], bias4[q][3]};
#pragma unroll
                for (int s = 0; s < 3; s++) {
                    float bv[8];
#pragma unroll
                    for (int h = 0; h < 2; h++)
#pragma unroll
                        for (int e = 0; e < 4; e++)
                            bv[h * 4 + e] = row8[s * 2 + h][pj + e];
                    s16x8 Bh, Bl;
                    split8(bv, &Bh, &Bl);
#pragma unroll
                    for (int q = 0; q < 4; q++) {
                        acc[q] = __builtin_amdgcn_mfma_f32_16x16x32_bf16(Ah[q][s], Bh, acc[q], 0, 0, 0);
                        acc[q] = __builtin_amdgcn_mfma_f32_16x16x32_bf16(Ah[q][s], Bl, acc[q], 0, 0, 0);
                        acc[q] = __builtin_amdgcn_mfma_f32_16x16x32_bf16(Al[q][s], Bh, acc[q], 0, 0, 0);
                    }
                }
                // in-lane fold: max + stats (no cross-lane ops)
#pragma unroll
                for (int q = 0; q < 4; q++) {
                    float m0 = acc[q][0], m1 = acc[q][1];
                    float m2 = acc[q][2], m3 = acc[q][3];
                    vmax[q][0] = fmaxf(vmax[q][0], m0);
                    vmax[q][1] = fmaxf(vmax[q][1], m1);
                    vmax[q][2] = fmaxf(vmax[q][2], m2);
                    vmax[q][3] = fmaxf(vmax[q][3], m3);
                    float sp = sgn4[q][0] * m0 + sgn4[q][1] * m1
                             + sgn4[q][2] * m2 + sgn4[q][3] * m3;
                    float sq = m0 * m0 + m1 * m1 + m2 * m2 + m3 * m3;
                    sA[q]  = fmaf(msk, sp, sA[q]);
                    ssA[q] = fmaf(msk, sq, ssA[q]);
                }
            }
        }
        // coalesced stores: lane p15 = pw
        if (valid) {
#pragma unroll
            for (int q = 0; q < 4; q++)
#pragma unroll
                for (int r = 0; r < 4; r++) {
                    int c = q * 16 + 4 * lg + r;
                    out[(((size_t)n * OC + c) * PH + ph) * PW + pw] = vmax[q][r];
                }
        }
    }

    // ================= edge cells (stats only, masked MFMA) =============
    // 32 per image: eb<16 -> right edge (cols 124-125, 8 rows x 2 cols);
    // eb>=16 -> bottom rows 124-125 (2 rows x 8 cols). Per-lane masked
    // accumulation -- reduction deferred to the single end butterfly.
#pragma unroll 1
    for (int t = 2 * wave; t < 2 * wave + 2; t++) {
        int eb = band * 8 + t;
        int posrow, poscol, evalid;
        if (eb < 16) {
            posrow = 8 * eb + (p15 >> 1);
            poscol = 124 + (p15 & 1);
            evalid = (posrow <= 125);
        } else {
            posrow = 124 + (p15 >> 3);
            poscol = 8 * (eb - 16) + (p15 & 7);
            evalid = (poscol <= 123);
        }

        f32x4 acc[4];
#pragma unroll
        for (int q = 0; q < 4; q++)
            acc[q] = (f32x4){bias4[q][0], bias4[q][1], bias4[q][2], bias4[q][3]};

#pragma unroll
        for (int s = 0; s < 3; s++) {
            float bv[8];
#pragma unroll
            for (int h = 0; h < 2; h++) {
                int sh = s * 2 + h;
                int xr = posrow + khA[sh]; if (xr > 127) xr = 127;
                const float* p = xn + icA[sh] * CSTR + xr * IW;
                int c0 = poscol;
                int c1 = c0 + 1; if (c1 > 127) c1 = 127;
                int c2 = c0 + 2; if (c2 > 127) c2 = 127;
                int c3 = c0 + 3; if (c3 > 127) c3 = 127;
                bv[h * 4 + 0] = p[c0]; bv[h * 4 + 1] = p[c1];
                bv[h * 4 + 2] = p[c2]; bv[h * 4 + 3] = p[c3];
            }
            s16x8 Bh, Bl;
            split8(bv, &Bh, &Bl);
#pragma unroll
            for (int q = 0; q < 4; q++) {
                acc[q] = __builtin_amdgcn_mfma_f32_16x16x32_bf16(Ah[q][s], Bh, acc[q], 0, 0, 0);
                acc[q] = __builtin_amdgcn_mfma_f32_16x16x32_bf16(Ah[q][s], Bl, acc[q], 0, 0, 0);
                acc[q] = __builtin_amdgcn_mfma_f32_16x16x32_bf16(Al[q][s], Bh, acc[q], 0, 0, 0);
            }
        }

        float vmask = evalid ? 1.f : 0.f;
#pragma unroll
        for (int q = 0; q < 4; q++) {
            float m0 = acc[q][0] * vmask, m1 = acc[q][1] * vmask;
            float m2 = acc[q][2] * vmask, m3 = acc[q][3] * vmask;
            sA[q]  += sgn4[q][0] * m0 + sgn4[q][1] * m1
                    + sgn4[q][2] * m2 + sgn4[q][3] * m3;
            ssA[q] += m0 * m0 + m1 * m1 + m2 * m2 + m3 * m3;
        }
    }

    // ---- ONE butterfly per block: reduce over the 16 p15-lanes ----
#pragma unroll
    for (int q = 0; q < 4; q++) {
        float sp = sA[q], sq = ssA[q];
#pragma unroll
        for (int o = 1; o < 16; o <<= 1) {
            sp += __shfl_xor(sp, o, 64);
            sq += __shfl_xor(sq, o, 64);
        }
        if (p15 == 0) {
            gsum[wave][q * 4 + lg][0] = sp;
            gsum[wave][q * 4 + lg][1] = sq;
        }
    }
    __syncthreads();
    if (tid < 32) {
        int g = tid >> 1, which = tid & 1;
        float v = gsum[0][g][which] + gsum[1][g][which]
                + gsum[2][g][which] + gsum[3][g][which];
        ws[((size_t)(n * NBAND + band) * NG + g) * 2 + which] = v;
    }
}

// PHASE 2: in-place affine + clamp over out (raw pooled signed-max).
__launch_bounds__(256)
__global__ void finalize_phase2(const float* __restrict__ gn_w,
                                const float* __restrict__ gn_b,
                                const float* __restrict__ scale,
                                const float* __restrict__ ws,
                                float* __restrict__ out) {
    const int total = N_IMG * OC * PH * PW;
    const float inv_count = 1.f / (float)(4 * 126 * 126);
    int stride = gridDim.x * 256;
    for (int i = blockIdx.x * 256 + threadIdx.x; i < total; i += stride) {
        int n = i / (OC * PH * PW);
        int rem = i - n * (OC * PH * PW);
        int c = rem / (PH * PW);
        int g = c >> 2;
        float S = 0.f, SS = 0.f;
#pragma unroll
        for (int bnd = 0; bnd < NBAND; bnd++) {
            size_t wb = ((size_t)(n * NBAND + bnd) * NG + g) * 2;
            S += ws[wb];
            SS += ws[wb + 1];
        }
        float mean = S * inv_count;
        float var = SS * inv_count - mean * mean;
        if (var < 0.f) var = 0.f;
        float rstd = rsqrtf(var + GN_EPS);
        float gw = gn_w[c], sc = scale[c];
        float a2 = rstd * fabsf(gw * sc);
        float b2 = (gn_b[c] - mean * rstd * gw) * sc;
        float v = fmaf(a2, out[i], b2);
        out[i] = fminf(fmaxf(v, 0.f), 1.f);
    }
}

extern "C" void kernel_launch(void* const* d_in, const int* in_sizes, int n_in,
                              void* d_out, int out_size, void* d_ws, size_t ws_size,
                              hipStream_t stream) {
    const float* x      = (const float*)d_in[0];
    const float* conv_w = (const float*)d_in[1];
    const float* conv_b = (const float*)d_in[2];
    const float* gn_w   = (const float*)d_in[3];
    const float* gn_b   = (const float*)d_in[4];
    const float* scale  = (const float*)d_in[5];
    float* out = (float*)d_out;
    float* ws  = (float*)d_ws;   // 512 * 16 * 2 floats = 64 KB

    hipLaunchKernelGGL(conv_pool_mfma_phase1, dim3(N_IMG * NBAND), dim3(256),
                       0, stream, x, conv_w, conv_b, gn_w, gn_b, scale, out, ws);
    hipLaunchKernelGGL(finalize_phase2, dim3(2048), dim3(256), 0, stream,
                       gn_w, gn_b, scale, ws, out);
}

// Round 15
// 292.406 us; speedup vs baseline: 1.5378x; 1.5378x over previous
//
#include <hip/hip_runtime.h>
#include <math.h>

// Problem constants
#define N_IMG 128
#define IC 8
#define IH 128
#define IW 128
#define OC 64
#define NG 16
#define PH 31
#define PW 31
#define GN_EPS 1e-5f
#define CSTR (IH * IW)      // channel stride in x
#define NBAND 4             // pool-row bands per image

typedef float f32x4 __attribute__((ext_vector_type(4)));
typedef short s16x8 __attribute__((ext_vector_type(8)));
typedef int   i32x4 __attribute__((ext_vector_type(4)));

// v_cvt_pk_bf16_f32: pack two f32 into one dword of 2 bf16 (RNE).
__device__ __forceinline__ unsigned cvt_pk_bf16(float a, float b) {
    unsigned r;
    asm("v_cvt_pk_bf16_f32 %0, %1, %2" : "=v"(r) : "v"(a), "v"(b));
    return r;
}
__device__ __forceinline__ float bf16lo_f(unsigned p) { return __uint_as_float(p << 16); }
__device__ __forceinline__ float bf16hi_f(unsigned p) { return __uint_as_float(p & 0xFFFF0000u); }

__device__ __forceinline__ s16x8 mk_frag(unsigned a, unsigned b, unsigned c, unsigned d) {
    union { i32x4 i; s16x8 s; } u;
    u.i = (i32x4){(int)a, (int)b, (int)c, (int)d};
    return u.s;
}

// split 8 f32 into hi/lo bf16 fragments: v ~= hi + lo to ~2^-17 rel.
__device__ __forceinline__ void split8(const float v[8], s16x8* hi, s16x8* lo) {
    unsigned h[4], l[4];
#pragma unroll
    for (int e = 0; e < 4; e++) {
        float a = v[2 * e], b = v[2 * e + 1];
        unsigned hp = cvt_pk_bf16(a, b);
        float ra = a - bf16lo_f(hp);
        float rb = b - bf16hi_f(hp);
        h[e] = hp;
        l[e] = cvt_pk_bf16(ra, rb);
    }
    *hi = mk_frag(h[0], h[1], h[2], h[3]);
    *lo = mk_frag(l[0], l[1], l[2], l[3]);
}

// PHASE 1 -- MFMA implicit-GEMM conv + pool-max + partial GN stats.
//
// ROUND-14 LESSON: holding all 4 channel-quad sets per wave (A-frags = 96
// VGPR) + row8 cache + vmax = ~240 live regs vs the 128 the allocator
// grants -> 1.06 GB of spill traffic, VALUBusy 10%. THIS VERSION:
// WAVE-PER-Q SPECIALIZATION -- wave w owns channel set q=w (16 channels)
// and processes ALL tiles of the band for it. A-frags 96->24, bias/sgn
// 32->8, acc 16->4, vmax 16->4: live set ~115, fits. Keeps the validated
// R14 transposed tile (lane p15 = pool cell): in-lane pool max (zero
// per-cell shuffles), ONE butterfly per block, aligned row8 gather,
// coalesced stores. Cost: B split8 per-wave instead of shared (4x) --
// ~30us of VALU across the machine vs 1GB of spill.
//
// Layout facts (HW-verified, R13 passed): A row / B col = lane&15;
// k-slot = 32*s + 16*h + (lane>>4)*4 + e; D: col = lane&15,
// row = (lane>>4)*4 + reg. K = ic*12 + kh*4 + kw (96 padded, kw=3 zero).
// Split-bf16: D += Ah*Bh + Ah*Bl + Al*Bh. Waves own disjoint GN groups
// (4q+lg) -> gsum needs no cross-wave sum.
__attribute__((amdgpu_waves_per_eu(2, 4)))
__launch_bounds__(256)
__global__ void conv_pool_mfma_phase1(const float* __restrict__ x,
                                      const float* __restrict__ conv_w,
                                      const float* __restrict__ conv_b,
                                      const float* __restrict__ gn_w,
                                      const float* __restrict__ gn_b,
                                      const float* __restrict__ scale,
                                      float* __restrict__ out,
                                      float* __restrict__ ws) {
    const int b = blockIdx.x;                  // 0..511
    const int wid = ((b & 7) << 6) | (b >> 3); // XCD swizzle (512 = 8x64)
    const int n = wid >> 2;
    const int band = wid & 3;
    const int tid = threadIdx.x;
    const int lane = tid & 63;
    const int q = tid >> 6;                    // wave index == channel set
    const int p15 = lane & 15;                 // A-row / B-col / D-col index
    const int lg = lane >> 4;                  // k-quad selector / D row group

    __shared__ float gsum[NG][2];              // disjoint per-wave groups

    const float* xn = x + (size_t)n * (IC * CSTR);

    // ---- per-lane k-quad decode: sh = s*2+half -> (ic, kh) ----
    int icA[6], khA[6], rowoffA[6];
#pragma unroll
    for (int sh = 0; sh < 6; sh++) {
        int s = sh >> 1, h = sh & 1;
        int k0 = 32 * s + 16 * h + 4 * lg;     // multiple of 4
        int ic = k0 / 12;
        int kk = k0 - 12 * ic;                 // 0,4,8
        int kh = kk >> 2;
        icA[sh] = ic; khA[sh] = kh;
        rowoffA[sh] = ic * CSTR + kh * IW;
    }

    // ---- A fragments for THIS wave's channel set only (24 VGPR) ----
    s16x8 Ah[3], Al[3];
    {
        int c = q * 16 + p15;
        float sg = (gn_w[c] * scale[c] >= 0.f) ? 1.f : -1.f;
#pragma unroll
        for (int s = 0; s < 3; s++) {
            float wf[8];
#pragma unroll
            for (int h = 0; h < 2; h++) {
                int sh = s * 2 + h;
                int ic = icA[sh], kh = khA[sh];
#pragma unroll
                for (int kw = 0; kw < 4; kw++)
                    wf[h * 4 + kw] = (kw < 3)
                        ? conv_w[c * (IC * 9) + ic * 9 + kh * 3 + kw] * sg
                        : 0.f;
            }
            split8(wf, &Ah[s], &Al[s]);
        }
    }

    // ---- bias/sign for the ACC layout channels (q*16 + lg*4 + r) ----
    float bias4[4], sgn4[4];
#pragma unroll
    for (int r = 0; r < 4; r++) {
        int c = q * 16 + 4 * lg + r;
        float sg = (gn_w[c] * scale[c] >= 0.f) ? 1.f : -1.f;
        sgn4[r] = sg;
        bias4[r] = conv_b[c] * sg;
    }

    float sA = 0.f, ssA = 0.f;

    // ================= main tiles: 16 cells per tile, lane p15 = cell ====
    // band<3: 8 pool rows x 2 tiles = 16; band 3: 7 rows -> 14 tiles.
    const int ntile = (band < 3) ? 16 : 14;
    const int phb = band * 8;

#pragma unroll 1
    for (int t = 0; t < ntile; t++) {
        const int ph = phb + (t >> 1);
        const int pw = (t & 1) * 16 + p15;
        const int valid = (pw <= 30);
        const int pwc = valid ? pw : 30;       // clamp for safe loads
        const float msk = valid ? 1.f : 0.f;
        const float* xtile = xn + (4 * ph) * IW + 4 * pwc;

        f32x4 vmax = (f32x4){-INFINITY, -INFINITY, -INFINITY, -INFINITY};

#pragma unroll
        for (int pi = 0; pi < 4; pi++) {
            // cache the 6 (s,h) x-rows: 8 aligned floats each (2x float4)
            float row8[6][8];
#pragma unroll
            for (int sh = 0; sh < 6; sh++) {
                const float* p = xtile + rowoffA[sh] + pi * IW;
                float4 a = *(const float4*)p;
                float4 bq = *(const float4*)(p + 4);
                row8[sh][0] = a.x;  row8[sh][1] = a.y;
                row8[sh][2] = a.z;  row8[sh][3] = a.w;
                row8[sh][4] = bq.x; row8[sh][5] = bq.y;
                row8[sh][6] = bq.z; row8[sh][7] = bq.w;
            }
#pragma unroll
            for (int pj = 0; pj < 4; pj++) {
                f32x4 acc = (f32x4){bias4[0], bias4[1], bias4[2], bias4[3]};
#pragma unroll
                for (int s = 0; s < 3; s++) {
                    float bv[8];
#pragma unroll
                    for (int e = 0; e < 4; e++) {
                        bv[e]     = row8[s * 2][pj + e];
                        bv[4 + e] = row8[s * 2 + 1][pj + e];
                    }
                    s16x8 Bh, Bl;
                    split8(bv, &Bh, &Bl);
                    acc = __builtin_amdgcn_mfma_f32_16x16x32_bf16(Ah[s], Bh, acc, 0, 0, 0);
                    acc = __builtin_amdgcn_mfma_f32_16x16x32_bf16(Ah[s], Bl, acc, 0, 0, 0);
                    acc = __builtin_amdgcn_mfma_f32_16x16x32_bf16(Al[s], Bh, acc, 0, 0, 0);
                }
                // in-lane fold: max + stats (no cross-lane ops)
                float m0 = acc[0], m1 = acc[1], m2 = acc[2], m3 = acc[3];
                vmax[0] = fmaxf(vmax[0], m0);
                vmax[1] = fmaxf(vmax[1], m1);
                vmax[2] = fmaxf(vmax[2], m2);
                vmax[3] = fmaxf(vmax[3], m3);
                float sp = sgn4[0] * m0 + sgn4[1] * m1
                         + sgn4[2] * m2 + sgn4[3] * m3;
                float sq = m0 * m0 + m1 * m1 + m2 * m2 + m3 * m3;
                sA  = fmaf(msk, sp, sA);
                ssA = fmaf(msk, sq, ssA);
            }
        }
        // coalesced stores: lane p15 = pw
        if (valid) {
#pragma unroll
            for (int r = 0; r < 4; r++) {
                int c = q * 16 + 4 * lg + r;
                out[(((size_t)n * OC + c) * PH + ph) * PW + pw] = vmax[r];
            }
        }
    }

    // ================= edge cells (stats only, masked MFMA) =============
    // 8 per band; each wave does all 8 for its q. eb<16 -> right edge
    // (cols 124-125, 8 rows x 2 cols); eb>=16 -> bottom rows 124-125
    // (2 rows x 8 cols). Per-lane masked accumulation; reduction deferred.
#pragma unroll 1
    for (int t = 0; t < 8; t++) {
        int eb = band * 8 + t;
        int posrow, poscol, evalid;
        if (eb < 16) {
            posrow = 8 * eb + (p15 >> 1);
            poscol = 124 + (p15 & 1);
            evalid = (posrow <= 125);
        } else {
            posrow = 124 + (p15 >> 3);
            poscol = 8 * (eb - 16) + (p15 & 7);
            evalid = (poscol <= 123);
        }

        f32x4 acc = (f32x4){bias4[0], bias4[1], bias4[2], bias4[3]};
#pragma unroll
        for (int s = 0; s < 3; s++) {
            float bv[8];
#pragma unroll
            for (int h = 0; h < 2; h++) {
                int sh = s * 2 + h;
                int xr = posrow + khA[sh]; if (xr > 127) xr = 127;
                const float* p = xn + icA[sh] * CSTR + xr * IW;
                int c0 = poscol;
                int c1 = c0 + 1; if (c1 > 127) c1 = 127;
                int c2 = c0 + 2; if (c2 > 127) c2 = 127;
                int c3 = c0 + 3; if (c3 > 127) c3 = 127;
                bv[h * 4 + 0] = p[c0]; bv[h * 4 + 1] = p[c1];
                bv[h * 4 + 2] = p[c2]; bv[h * 4 + 3] = p[c3];
            }
            s16x8 Bh, Bl;
            split8(bv, &Bh, &Bl);
            acc = __builtin_amdgcn_mfma_f32_16x16x32_bf16(Ah[s], Bh, acc, 0, 0, 0);
            acc = __builtin_amdgcn_mfma_f32_16x16x32_bf16(Ah[s], Bl, acc, 0, 0, 0);
            acc = __builtin_amdgcn_mfma_f32_16x16x32_bf16(Al[s], Bh, acc, 0, 0, 0);
        }

        float vmask = evalid ? 1.f : 0.f;
        float m0 = acc[0] * vmask, m1 = acc[1] * vmask;
        float m2 = acc[2] * vmask, m3 = acc[3] * vmask;
        sA  += sgn4[0] * m0 + sgn4[1] * m1 + sgn4[2] * m2 + sgn4[3] * m3;
        ssA += m0 * m0 + m1 * m1 + m2 * m2 + m3 * m3;
    }

    // ---- ONE butterfly per block: reduce over the 16 p15-lanes ----
    {
        float sp = sA, sq = ssA;
#pragma unroll
        for (int o = 1; o < 16; o <<= 1) {
            sp += __shfl_xor(sp, o, 64);
            sq += __shfl_xor(sq, o, 64);
        }
        if (p15 == 0) {                        // lanes 0,16,32,48: lg=0..3
            gsum[q * 4 + lg][0] = sp;          // disjoint across waves
            gsum[q * 4 + lg][1] = sq;
        }
    }
    __syncthreads();
    if (tid < 32) {
        int g = tid >> 1, which = tid & 1;
        ws[((size_t)(n * NBAND + band) * NG + g) * 2 + which] = gsum[g][which];
    }
}

// PHASE 2: in-place affine + clamp over out (raw pooled signed-max).
__launch_bounds__(256)
__global__ void finalize_phase2(const float* __restrict__ gn_w,
                                const float* __restrict__ gn_b,
                                const float* __restrict__ scale,
                                const float* __restrict__ ws,
                                float* __restrict__ out) {
    const int total = N_IMG * OC * PH * PW;
    const float inv_count = 1.f / (float)(4 * 126 * 126);
    int stride = gridDim.x * 256;
    for (int i = blockIdx.x * 256 + threadIdx.x; i < total; i += stride) {
        int n = i / (OC * PH * PW);
        int rem = i - n * (OC * PH * PW);
        int c = rem / (PH * PW);
        int g = c >> 2;
        float S = 0.f, SS = 0.f;
#pragma unroll
        for (int bnd = 0; bnd < NBAND; bnd++) {
            size_t wb = ((size_t)(n * NBAND + bnd) * NG + g) * 2;
            S += ws[wb];
            SS += ws[wb + 1];
        }
        float mean = S * inv_count;
        float var = SS * inv_count - mean * mean;
        if (var < 0.f) var = 0.f;
        float rstd = rsqrtf(var + GN_EPS);
        float gw = gn_w[c], sc = scale[c];
        float a2 = rstd * fabsf(gw * sc);
        float b2 = (gn_b[c] - mean * rstd * gw) * sc;
        float v = fmaf(a2, out[i], b2);
        out[i] = fminf(fmaxf(v, 0.f), 1.f);
    }
}

extern "C" void kernel_launch(void* const* d_in, const int* in_sizes, int n_in,
                              void* d_out, int out_size, void* d_ws, size_t ws_size,
                              hipStream_t stream) {
    const float* x      = (const float*)d_in[0];
    const float* conv_w = (const float*)d_in[1];
    const float* conv_b = (const float*)d_in[2];
    const float* gn_w   = (const float*)d_in[3];
    const float* gn_b   = (const float*)d_in[4];
    const float* scale  = (const float*)d_in[5];
    float* out = (float*)d_out;
    float* ws  = (float*)d_ws;   // 512 * 16 * 2 floats = 64 KB

    hipLaunchKernelGGL(conv_pool_mfma_phase1, dim3(N_IMG * NBAND), dim3(256),
                       0, stream, x, conv_w, conv_b, gn_w, gn_b, scale, out, ws);
    hipLaunchKernelGGL(finalize_phase2, dim3(2048), dim3(256), 0, stream,
                       gn_w, gn_b, scale, ws, out);
}

// Round 16
// 288.080 us; speedup vs baseline: 1.5609x; 1.0150x over previous
//
#include <hip/hip_runtime.h>
#include <math.h>

// Problem constants
#define N_IMG 128
#define IC 8
#define IH 128
#define IW 128
#define OC 64
#define NG 16
#define PH 31
#define PW 31
#define GN_EPS 1e-5f
#define CSTR (IH * IW)      // channel stride in x
#define NBAND 8             // pool-row bands per image (4 rows; band 7: 3)

typedef float f32x4 __attribute__((ext_vector_type(4)));
typedef short s16x8 __attribute__((ext_vector_type(8)));
typedef int   i32x4 __attribute__((ext_vector_type(4)));

// v_cvt_pk_bf16_f32: pack two f32 into one dword of 2 bf16 (RNE).
__device__ __forceinline__ unsigned cvt_pk_bf16(float a, float b) {
    unsigned r;
    asm("v_cvt_pk_bf16_f32 %0, %1, %2" : "=v"(r) : "v"(a), "v"(b));
    return r;
}
__device__ __forceinline__ float bf16lo_f(unsigned p) { return __uint_as_float(p << 16); }
__device__ __forceinline__ float bf16hi_f(unsigned p) { return __uint_as_float(p & 0xFFFF0000u); }

__device__ __forceinline__ s16x8 mk_frag(unsigned a, unsigned b, unsigned c, unsigned d) {
    union { i32x4 i; s16x8 s; } u;
    u.i = (i32x4){(int)a, (int)b, (int)c, (int)d};
    return u.s;
}

// split 8 f32 into hi/lo bf16 fragments: v ~= hi + lo to ~2^-17 rel.
__device__ __forceinline__ void split8(const float v[8], s16x8* hi, s16x8* lo) {
    unsigned h[4], l[4];
#pragma unroll
    for (int e = 0; e < 4; e++) {
        float a = v[2 * e], b = v[2 * e + 1];
        unsigned hp = cvt_pk_bf16(a, b);
        float ra = a - bf16lo_f(hp);
        float rb = b - bf16hi_f(hp);
        h[e] = hp;
        l[e] = cvt_pk_bf16(ra, rb);
    }
    *hi = mk_frag(h[0], h[1], h[2], h[3]);
    *lo = mk_frag(l[0], l[1], l[2], l[3]);
}

// PHASE 1 -- MFMA implicit-GEMM conv + pool-max + partial GN stats.
//
// R15 (passed, 193us, spill-free): wave-per-q specialization + transposed
// tile (lane p15 = pool cell; in-lane pool max, ONE butterfly per block,
// aligned row8 gather, coalesced stores). Counters showed 111us of issue
// (79 VALU + 32 MFMA) in 193us with occupancy 16% -- the 512-block grid
// put only 2 blocks/CU. ROUND-16 CHANGE: NBAND 4->8 (bands of 4 pool rows)
// -> 1024 blocks = 4 blocks/CU queued, ~2x resident waves, half the
// serial tail. Body/numerics byte-identical to R15.
//
// Layout facts (HW-verified, R13/R15 passed): A row / B col = lane&15;
// k-slot = 32*s + 16*h + (lane>>4)*4 + e; D: col = lane&15,
// row = (lane>>4)*4 + reg. K = ic*12 + kh*4 + kw (96 padded, kw=3 zero).
// Split-bf16: D += Ah*Bh + Ah*Bl + Al*Bh. Waves own disjoint GN groups
// (4q+lg) -> gsum needs no cross-wave sum.
__attribute__((amdgpu_waves_per_eu(2, 4)))
__launch_bounds__(256)
__global__ void conv_pool_mfma_phase1(const float* __restrict__ x,
                                      const float* __restrict__ conv_w,
                                      const float* __restrict__ conv_b,
                                      const float* __restrict__ gn_w,
                                      const float* __restrict__ gn_b,
                                      const float* __restrict__ scale,
                                      float* __restrict__ out,
                                      float* __restrict__ ws) {
    const int b = blockIdx.x;                  // 0..1023
    const int wid = ((b & 7) << 7) | (b >> 3); // XCD swizzle (1024 = 8x128)
    const int n = wid >> 3;
    const int band = wid & 7;
    const int tid = threadIdx.x;
    const int lane = tid & 63;
    const int q = tid >> 6;                    // wave index == channel set
    const int p15 = lane & 15;                 // A-row / B-col / D-col index
    const int lg = lane >> 4;                  // k-quad selector / D row group

    __shared__ float gsum[NG][2];              // disjoint per-wave groups

    const float* xn = x + (size_t)n * (IC * CSTR);

    // ---- per-lane k-quad decode: sh = s*2+half -> (ic, kh) ----
    int icA[6], khA[6], rowoffA[6];
#pragma unroll
    for (int sh = 0; sh < 6; sh++) {
        int s = sh >> 1, h = sh & 1;
        int k0 = 32 * s + 16 * h + 4 * lg;     // multiple of 4
        int ic = k0 / 12;
        int kk = k0 - 12 * ic;                 // 0,4,8
        int kh = kk >> 2;
        icA[sh] = ic; khA[sh] = kh;
        rowoffA[sh] = ic * CSTR + kh * IW;
    }

    // ---- A fragments for THIS wave's channel set only (24 VGPR) ----
    s16x8 Ah[3], Al[3];
    {
        int c = q * 16 + p15;
        float sg = (gn_w[c] * scale[c] >= 0.f) ? 1.f : -1.f;
#pragma unroll
        for (int s = 0; s < 3; s++) {
            float wf[8];
#pragma unroll
            for (int h = 0; h < 2; h++) {
                int sh = s * 2 + h;
                int ic = icA[sh], kh = khA[sh];
#pragma unroll
                for (int kw = 0; kw < 4; kw++)
                    wf[h * 4 + kw] = (kw < 3)
                        ? conv_w[c * (IC * 9) + ic * 9 + kh * 3 + kw] * sg
                        : 0.f;
            }
            split8(wf, &Ah[s], &Al[s]);
        }
    }

    // ---- bias/sign for the ACC layout channels (q*16 + lg*4 + r) ----
    float bias4[4], sgn4[4];
#pragma unroll
    for (int r = 0; r < 4; r++) {
        int c = q * 16 + 4 * lg + r;
        float sg = (gn_w[c] * scale[c] >= 0.f) ? 1.f : -1.f;
        sgn4[r] = sg;
        bias4[r] = conv_b[c] * sg;
    }

    float sA = 0.f, ssA = 0.f;

    // ================= main tiles: 16 cells per tile, lane p15 = cell ====
    // bands 0-6: 4 pool rows x 2 tiles = 8; band 7: 3 rows -> 6 tiles.
    const int ntile = (band < 7) ? 8 : 6;
    const int phb = band * 4;

#pragma unroll 1
    for (int t = 0; t < ntile; t++) {
        const int ph = phb + (t >> 1);
        const int pw = (t & 1) * 16 + p15;
        const int valid = (pw <= 30);
        const int pwc = valid ? pw : 30;       // clamp for safe loads
        const float msk = valid ? 1.f : 0.f;
        const float* xtile = xn + (4 * ph) * IW + 4 * pwc;

        f32x4 vmax = (f32x4){-INFINITY, -INFINITY, -INFINITY, -INFINITY};

#pragma unroll
        for (int pi = 0; pi < 4; pi++) {
            // cache the 6 (s,h) x-rows: 8 aligned floats each (2x float4)
            float row8[6][8];
#pragma unroll
            for (int sh = 0; sh < 6; sh++) {
                const float* p = xtile + rowoffA[sh] + pi * IW;
                float4 a = *(const float4*)p;
                float4 bq = *(const float4*)(p + 4);
                row8[sh][0] = a.x;  row8[sh][1] = a.y;
                row8[sh][2] = a.z;  row8[sh][3] = a.w;
                row8[sh][4] = bq.x; row8[sh][5] = bq.y;
                row8[sh][6] = bq.z; row8[sh][7] = bq.w;
            }
#pragma unroll
            for (int pj = 0; pj < 4; pj++) {
                f32x4 acc = (f32x4){bias4[0], bias4[1], bias4[2], bias4[3]};
#pragma unroll
                for (int s = 0; s < 3; s++) {
                    float bv[8];
#pragma unroll
                    for (int e = 0; e < 4; e++) {
                        bv[e]     = row8[s * 2][pj + e];
                        bv[4 + e] = row8[s * 2 + 1][pj + e];
                    }
                    s16x8 Bh, Bl;
                    split8(bv, &Bh, &Bl);
                    acc = __builtin_amdgcn_mfma_f32_16x16x32_bf16(Ah[s], Bh, acc, 0, 0, 0);
                    acc = __builtin_amdgcn_mfma_f32_16x16x32_bf16(Ah[s], Bl, acc, 0, 0, 0);
                    acc = __builtin_amdgcn_mfma_f32_16x16x32_bf16(Al[s], Bh, acc, 0, 0, 0);
                }
                // in-lane fold: max + stats (no cross-lane ops)
                float m0 = acc[0], m1 = acc[1], m2 = acc[2], m3 = acc[3];
                vmax[0] = fmaxf(vmax[0], m0);
                vmax[1] = fmaxf(vmax[1], m1);
                vmax[2] = fmaxf(vmax[2], m2);
                vmax[3] = fmaxf(vmax[3], m3);
                float sp = sgn4[0] * m0 + sgn4[1] * m1
                         + sgn4[2] * m2 + sgn4[3] * m3;
                float sq = m0 * m0 + m1 * m1 + m2 * m2 + m3 * m3;
                sA  = fmaf(msk, sp, sA);
                ssA = fmaf(msk, sq, ssA);
            }
        }
        // coalesced stores: lane p15 = pw
        if (valid) {
#pragma unroll
            for (int r = 0; r < 4; r++) {
                int c = q * 16 + 4 * lg + r;
                out[(((size_t)n * OC + c) * PH + ph) * PW + pw] = vmax[r];
            }
        }
    }

    // ================= edge cells (stats only, masked MFMA) =============
    // 32 per image -> 4 per band; each wave does all 4 for its q.
    // eb<16: right edge (cols 124-125, 8 rows x 2 cols);
    // eb>=16: bottom rows 124-125 (2 rows x 8 cols).
#pragma unroll 1
    for (int t = 0; t < 4; t++) {
        int eb = band * 4 + t;
        int posrow, poscol, evalid;
        if (eb < 16) {
            posrow = 8 * eb + (p15 >> 1);
            poscol = 124 + (p15 & 1);
            evalid = (posrow <= 125);
        } else {
            posrow = 124 + (p15 >> 3);
            poscol = 8 * (eb - 16) + (p15 & 7);
            evalid = (poscol <= 123);
        }

        f32x4 acc = (f32x4){bias4[0], bias4[1], bias4[2], bias4[3]};
#pragma unroll
        for (int s = 0; s < 3; s++) {
            float bv[8];
#pragma unroll
            for (int h = 0; h < 2; h++) {
                int sh = s * 2 + h;
                int xr = posrow + khA[sh]; if (xr > 127) xr = 127;
                const float* p = xn + icA[sh] * CSTR + xr * IW;
                int c0 = poscol;
                int c1 = c0 + 1; if (c1 > 127) c1 = 127;
                int c2 = c0 + 2; if (c2 > 127) c2 = 127;
                int c3 = c0 + 3; if (c3 > 127) c3 = 127;
                bv[h * 4 + 0] = p[c0]; bv[h * 4 + 1] = p[c1];
                bv[h * 4 + 2] = p[c2]; bv[h * 4 + 3] = p[c3];
            }
            s16x8 Bh, Bl;
            split8(bv, &Bh, &Bl);
            acc = __builtin_amdgcn_mfma_f32_16x16x32_bf16(Ah[s], Bh, acc, 0, 0, 0);
            acc = __builtin_amdgcn_mfma_f32_16x16x32_bf16(Ah[s], Bl, acc, 0, 0, 0);
            acc = __builtin_amdgcn_mfma_f32_16x16x32_bf16(Al[s], Bh, acc, 0, 0, 0);
        }

        float vmask = evalid ? 1.f : 0.f;
        float m0 = acc[0] * vmask, m1 = acc[1] * vmask;
        float m2 = acc[2] * vmask, m3 = acc[3] * vmask;
        sA  += sgn4[0] * m0 + sgn4[1] * m1 + sgn4[2] * m2 + sgn4[3] * m3;
        ssA += m0 * m0 + m1 * m1 + m2 * m2 + m3 * m3;
    }

    // ---- ONE butterfly per block: reduce over the 16 p15-lanes ----
    {
        float sp = sA, sq = ssA;
#pragma unroll
        for (int o = 1; o < 16; o <<= 1) {
            sp += __shfl_xor(sp, o, 64);
            sq += __shfl_xor(sq, o, 64);
        }
        if (p15 == 0) {                        // lanes 0,16,32,48: lg=0..3
            gsum[q * 4 + lg][0] = sp;          // disjoint across waves
            gsum[q * 4 + lg][1] = sq;
        }
    }
    __syncthreads();
    if (tid < 32) {
        int g = tid >> 1, which = tid & 1;
        ws[((size_t)(n * NBAND + band) * NG + g) * 2 + which] = gsum[g][which];
    }
}

// PHASE 2: in-place affine + clamp over out (raw pooled signed-max).
__launch_bounds__(256)
__global__ void finalize_phase2(const float* __restrict__ gn_w,
                                const float* __restrict__ gn_b,
                                const float* __restrict__ scale,
                                const float* __restrict__ ws,
                                float* __restrict__ out) {
    const int total = N_IMG * OC * PH * PW;
    const float inv_count = 1.f / (float)(4 * 126 * 126);
    int stride = gridDim.x * 256;
    for (int i = blockIdx.x * 256 + threadIdx.x; i < total; i += stride) {
        int n = i / (OC * PH * PW);
        int rem = i - n * (OC * PH * PW);
        int c = rem / (PH * PW);
        int g = c >> 2;
        float S = 0.f, SS = 0.f;
#pragma unroll
        for (int bnd = 0; bnd < NBAND; bnd++) {
            size_t wb = ((size_t)(n * NBAND + bnd) * NG + g) * 2;
            S += ws[wb];
            SS += ws[wb + 1];
        }
        float mean = S * inv_count;
        float var = SS * inv_count - mean * mean;
        if (var < 0.f) var = 0.f;
        float rstd = rsqrtf(var + GN_EPS);
        float gw = gn_w[c], sc = scale[c];
        float a2 = rstd * fabsf(gw * sc);
        float b2 = (gn_b[c] - mean * rstd * gw) * sc;
        float v = fmaf(a2, out[i], b2);
        out[i] = fminf(fmaxf(v, 0.f), 1.f);
    }
}

extern "C" void kernel_launch(void* const* d_in, const int* in_sizes, int n_in,
                              void* d_out, int out_size, void* d_ws, size_t ws_size,
                              hipStream_t stream) {
    const float* x      = (const float*)d_in[0];
    const float* conv_w = (const float*)d_in[1];
    const float* conv_b = (const float*)d_in[2];
    const float* gn_w   = (const float*)d_in[3];
    const float* gn_b   = (const float*)d_in[4];
    const float* scale  = (const float*)d_in[5];
    float* out = (float*)d_out;
    float* ws  = (float*)d_ws;   // 1024 * 16 * 2 floats = 128 KB

    hipLaunchKernelGGL(conv_pool_mfma_phase1, dim3(N_IMG * NBAND), dim3(256),
                       0, stream, x, conv_w, conv_b, gn_w, gn_b, scale, out, ws);
    hipLaunchKernelGGL(finalize_phase2, dim3(2048), dim3(256), 0, stream,
                       gn_w, gn_b, scale, ws, out);
}